// Round 8
// baseline (12.335 us; speedup 1.0000x reference)
//
#include <hip/hip_runtime.h>
#include <math.h>

// LDPC BP decode, fixed (3x7) H:
//   row A: vars {0,2,4,6}   v0 deg-1
//   row B: vars {1,2,5,6}   v1 deg-1
//   row C: vars {3,4,5,6}   v3 deg-1
// One thread per element, fully unrolled, all state in registers.
//
// MIDDLE ITERATIONS RUN ENTIRELY IN p-SPACE (p = tanh(m/2)):
//   extrinsic product y = prod of other p's  == tanh(c/2)
//   variable update m' = L + sum(c_other)  ==  Mobius combine:
//       P' = (pL + y) / (1 + pL*y)     [1 rcp + 3 full ops]
//   clamped to [-1,1] with v_med3 (1-ulp rcp overshoot would NaN the
//   final log2(1-y)). Saturation matches numpy tanh: p -> +-1.0 exactly
//   at |m|>=18, preserving the c<=17.33 ceiling that sets the output scale.
// FINAL ITERATION leaves p-space (P-repr saturates at |tot|>36 < max|ref|~39.5):
//   c2 = log2(1+y) - log2(1-y)  (validated R6 form, Sterbenz-exact near sat)
//   tot2 = L2 + sum c2 (R6 add order), out = tot2 * ln2.
// Issue model (fit R4/R6/R7): trans ~7.2cyc, full ~3cyc; this cuts
// full-rate 600->~330 and trans 110->86.

#define LOG2E 1.4426950408889634f
#define LN2   0.6931471805599453f

// p = tanh(m/2) from log2-domain LLR, validated grid path (bit-identical
// magnitude to rounds 4-6: t<=1 always since |L2|)
__device__ __forceinline__ float p_of_llr(float L2) {
    float t  = __builtin_amdgcn_exp2f(-fabsf(L2));
    float u  = __builtin_amdgcn_rcpf(1.0f + t);
    float pm = __builtin_fmaf(-2.0f, t * u, 1.0f);
    return __builtin_copysignf(pm, L2);
}

// tanh addition: comb(a,b) = tanh(atanh(a)+atanh(b)) = (a+b)/(1+ab), clamped
__device__ __forceinline__ float comb(float a, float b) {
    float num = a + b;
    float den = __builtin_fmaf(a, b, 1.0f);
    float r   = num * __builtin_amdgcn_rcpf(den);
    return __builtin_amdgcn_fmed3f(r, -1.0f, 1.0f);
}

// c in log2 units from y = tanh(c/2)
__device__ __forceinline__ float c_of(float y) {
    return __builtin_amdgcn_logf(1.0f + y) - __builtin_amdgcn_logf(1.0f - y);
}

// tot2 pre-filled with L2 (covers iters==0); iters constant-folds at the
// iters==5 call site -> full unroll
__device__ __forceinline__ void decode(int iters, const float L2[7], float tot2[7]) {
    if (iters <= 0) return;

    float pL0 = p_of_llr(L2[0]);
    float pL1 = p_of_llr(L2[1]);
    float pL2v = p_of_llr(L2[2]);
    float pL3 = p_of_llr(L2[3]);
    float pL4v = p_of_llr(L2[4]);
    float pL5v = p_of_llr(L2[5]);
    float pL6v = p_of_llr(L2[6]);

    // edge p-state (init: messages = L); deg-1 rows factors pL0/pL1/pL3 frozen
    float pA2 = pL2v, pA4 = pL4v, pA6 = pL6v;
    float pB2 = pL2v, pB5 = pL5v, pB6 = pL6v;
    float pC4 = pL4v, pC5 = pL5v, pC6 = pL6v;

    for (int it = 0; it < iters - 1; ++it) {
        // extrinsic products (5 muls/row)
        float gA = pL0 * pA2, bA = pA4 * pA6;
        float yA2 = pL0 * bA, yA4 = gA * pA6, yA6 = gA * pA4;
        float gB = pL1 * pB2, bB = pB5 * pB6;
        float yB2 = pL1 * bB, yB5 = gB * pB6, yB6 = gB * pB5;
        float gC = pL3 * pC4, bC = pC5 * pC6;
        float yC4 = pL3 * bC, yC5 = gC * pC6, yC6 = gC * pC5;

        // Mobius variable updates: P_edge = comb(pL_var, y's of other rows)
        pA2 = comb(pL2v, yB2);
        pB2 = comb(pL2v, yA2);
        pA4 = comb(pL4v, yC4);
        pC4 = comb(pL4v, yA4);
        pB5 = comb(pL5v, yC5);
        pC5 = comb(pL5v, yB5);
        pA6 = comb(comb(pL6v, yB6), yC6);
        pB6 = comb(comb(pL6v, yA6), yC6);
        pC6 = comb(comb(pL6v, yA6), yB6);
    }

    // final iteration: all 12 extrinsics, c's in log2 units, linear totals
    {
        float fA = pL0 * pA2, bA = pA4 * pA6;
        float yA0 = pA2 * bA, yA2 = pL0 * bA, yA4 = fA * pA6, yA6 = fA * pA4;
        float fB = pL1 * pB2, bB = pB5 * pB6;
        float yB1 = pB2 * bB, yB2 = pL1 * bB, yB5 = fB * pB6, yB6 = fB * pB5;
        float fC = pL3 * pC4, bC = pC5 * pC6;
        float yC3 = pC4 * bC, yC4 = pL3 * bC, yC5 = fC * pC6, yC6 = fC * pC5;

        float cA0 = c_of(yA0), cA2 = c_of(yA2), cA4 = c_of(yA4), cA6 = c_of(yA6);
        float cB1 = c_of(yB1), cB2 = c_of(yB2), cB5 = c_of(yB5), cB6 = c_of(yB6);
        float cC3 = c_of(yC3), cC4 = c_of(yC4), cC5 = c_of(yC5), cC6 = c_of(yC6);

        tot2[0] = L2[0] + cA0;
        tot2[1] = L2[1] + cB1;
        tot2[3] = L2[3] + cC3;
        tot2[2] = (L2[2] + cA2) + cB2;
        tot2[4] = (L2[4] + cA4) + cC4;
        tot2[5] = (L2[5] + cB5) + cC5;
        tot2[6] = ((L2[6] + cA6) + cB6) + cC6;
    }
}

__global__ __launch_bounds__(256) void ldpc_bp_kernel(
        const float* __restrict__ llr,
        const int*   __restrict__ iters_p,
        float*       __restrict__ out,
        int B) {
    int b = blockIdx.x * blockDim.x + threadIdx.x;
    if (b >= B) return;
    const int iters = iters_p[0];

    const float* Lp = llr + (size_t)b * 7;
    float L2[7], tot2[7];
#pragma unroll
    for (int j = 0; j < 7; ++j) {
        L2[j]  = Lp[j] * LOG2E;   // log2-domain LLR
        tot2[j] = L2[j];          // iters==0 fallback
    }

    if (iters == 5) {
        decode(5, L2, tot2);      // constant trip count -> full unroll
    } else {
        decode(iters, L2, tot2);
    }

    float* Op = out + (size_t)b * 7;
#pragma unroll
    for (int j = 0; j < 7; ++j) Op[j] = tot2[j] * LN2;
}

extern "C" void kernel_launch(void* const* d_in, const int* in_sizes, int n_in,
                              void* d_out, int out_size, void* d_ws, size_t ws_size,
                              hipStream_t stream) {
    (void)n_in; (void)d_ws; (void)ws_size;
    const float* llr  = (const float*)d_in[0];
    const int*   mi   = (const int*)d_in[1];
    float*       out  = (float*)d_out;
    const int B = in_sizes[0] / 7;
    const int block = 256;
    const int grid = (B + block - 1) / block;
    ldpc_bp_kernel<<<grid, block, 0, stream>>>(llr, mi, out, B);
}

// Round 9
// 11.523 us; speedup vs baseline: 1.0705x; 1.0705x over previous
//
#include <hip/hip_runtime.h>
#include <math.h>

// LDPC BP decode, fixed (3x7) H:
//   row A: vars {0,2,4,6}   v0 deg-1
//   row B: vars {1,2,5,6}   v1 deg-1
//   row C: vars {3,4,5,6}   v3 deg-1
// One thread per element; compute identical to round 8 (p-space Mobius
// middle iterations, log-domain final iteration).
//
// NEW this round: wave-coalesced global I/O via LDS staging.
//   Each wave owns dwords [waveElemBase*7, +448): loads them with 7
//   fully-coalesced global_load_dword (lane l, beat j -> dword j*64+l,
//   28 fully-used 64B transactions per wave vs ~196 for the old
//   stride-28B scalar pattern), parks them in a wave-private LDS slice,
//   then each thread ds_reads its 7 floats (dword addr l*7+j: stride 7
//   is coprime to 32 -> bank-conflict-free; 2 lanes/bank = free).
//   Store path mirrors it. Wave-private slices -> no __syncthreads.

#define LOG2E 1.4426950408889634f
#define LN2   0.6931471805599453f

// p = tanh(m/2) from log2-domain LLR (validated grid path, t<=1 branch)
__device__ __forceinline__ float p_of_llr(float L2) {
    float t  = __builtin_amdgcn_exp2f(-fabsf(L2));
    float u  = __builtin_amdgcn_rcpf(1.0f + t);
    float pm = __builtin_fmaf(-2.0f, t * u, 1.0f);
    return __builtin_copysignf(pm, L2);
}

// tanh addition: comb(a,b) = (a+b)/(1+ab), clamped to [-1,1]
__device__ __forceinline__ float comb(float a, float b) {
    float num = a + b;
    float den = __builtin_fmaf(a, b, 1.0f);
    float r   = num * __builtin_amdgcn_rcpf(den);
    return __builtin_amdgcn_fmed3f(r, -1.0f, 1.0f);
}

// c in log2 units from y = tanh(c/2)
__device__ __forceinline__ float c_of(float y) {
    return __builtin_amdgcn_logf(1.0f + y) - __builtin_amdgcn_logf(1.0f - y);
}

// tot2 pre-filled with L2 (covers iters==0); iters constant-folds at the
// iters==5 call site -> full unroll
__device__ __forceinline__ void decode(int iters, const float L2[7], float tot2[7]) {
    if (iters <= 0) return;

    float pL0  = p_of_llr(L2[0]);
    float pL1  = p_of_llr(L2[1]);
    float pL2v = p_of_llr(L2[2]);
    float pL3  = p_of_llr(L2[3]);
    float pL4v = p_of_llr(L2[4]);
    float pL5v = p_of_llr(L2[5]);
    float pL6v = p_of_llr(L2[6]);

    float pA2 = pL2v, pA4 = pL4v, pA6 = pL6v;
    float pB2 = pL2v, pB5 = pL5v, pB6 = pL6v;
    float pC4 = pL4v, pC5 = pL5v, pC6 = pL6v;

    for (int it = 0; it < iters - 1; ++it) {
        float gA = pL0 * pA2, bA = pA4 * pA6;
        float yA2 = pL0 * bA, yA4 = gA * pA6, yA6 = gA * pA4;
        float gB = pL1 * pB2, bB = pB5 * pB6;
        float yB2 = pL1 * bB, yB5 = gB * pB6, yB6 = gB * pB5;
        float gC = pL3 * pC4, bC = pC5 * pC6;
        float yC4 = pL3 * bC, yC5 = gC * pC6, yC6 = gC * pC5;

        pA2 = comb(pL2v, yB2);
        pB2 = comb(pL2v, yA2);
        pA4 = comb(pL4v, yC4);
        pC4 = comb(pL4v, yA4);
        pB5 = comb(pL5v, yC5);
        pC5 = comb(pL5v, yB5);
        pA6 = comb(comb(pL6v, yB6), yC6);
        pB6 = comb(comb(pL6v, yA6), yC6);
        pC6 = comb(comb(pL6v, yA6), yB6);
    }

    {
        float fA = pL0 * pA2, bA = pA4 * pA6;
        float yA0 = pA2 * bA, yA2 = pL0 * bA, yA4 = fA * pA6, yA6 = fA * pA4;
        float fB = pL1 * pB2, bB = pB5 * pB6;
        float yB1 = pB2 * bB, yB2 = pL1 * bB, yB5 = fB * pB6, yB6 = fB * pB5;
        float fC = pL3 * pC4, bC = pC5 * pC6;
        float yC3 = pC4 * bC, yC4 = pL3 * bC, yC5 = fC * pC6, yC6 = fC * pC5;

        float cA0 = c_of(yA0), cA2 = c_of(yA2), cA4 = c_of(yA4), cA6 = c_of(yA6);
        float cB1 = c_of(yB1), cB2 = c_of(yB2), cB5 = c_of(yB5), cB6 = c_of(yB6);
        float cC3 = c_of(yC3), cC4 = c_of(yC4), cC5 = c_of(yC5), cC6 = c_of(yC6);

        tot2[0] = L2[0] + cA0;
        tot2[1] = L2[1] + cB1;
        tot2[3] = L2[3] + cC3;
        tot2[2] = (L2[2] + cA2) + cB2;
        tot2[4] = (L2[4] + cA4) + cC4;
        tot2[5] = (L2[5] + cB5) + cC5;
        tot2[6] = ((L2[6] + cA6) + cB6) + cC6;
    }
}

__global__ __launch_bounds__(256) void ldpc_bp_kernel(
        const float* __restrict__ llr,
        const int*   __restrict__ iters_p,
        float*       __restrict__ out,
        int B) {
    __shared__ float lds[4 * 448];           // one 448-dword slice per wave

    const int tid  = threadIdx.x;
    const int wave = tid >> 6;
    const int lane = tid & 63;
    const int waveElemBase = blockIdx.x * 256 + wave * 64;
    const long dwBase   = (long)waveElemBase * 7;
    const long total_dw = (long)B * 7;
    float* wlds = &lds[wave * 448];

    // ---- coalesced load: 7 beats, lane l takes dword j*64+l ----
#pragma unroll
    for (int j = 0; j < 7; ++j) {
        int  o = j * 64 + lane;
        long g = dwBase + o;
        wlds[o] = (g < total_dw) ? llr[g] : 0.0f;
    }

    const int   iters = iters_p[0];
    const int   b     = waveElemBase + lane;

    float L2[7], tot2[7];
#pragma unroll
    for (int j = 0; j < 7; ++j) {
        L2[j]  = wlds[lane * 7 + j] * LOG2E;   // log2-domain LLR
        tot2[j] = L2[j];                       // iters==0 fallback
    }

    if (iters == 5) {
        decode(5, L2, tot2);                   // constant trip -> full unroll
    } else {
        decode(iters, L2, tot2);
    }

    // ---- coalesced store via the same wave-private LDS slice ----
#pragma unroll
    for (int j = 0; j < 7; ++j) {
        wlds[lane * 7 + j] = tot2[j] * LN2;
    }
#pragma unroll
    for (int j = 0; j < 7; ++j) {
        int  o = j * 64 + lane;
        long g = dwBase + o;
        if (g < total_dw) out[g] = wlds[o];
    }
    (void)b;
}

extern "C" void kernel_launch(void* const* d_in, const int* in_sizes, int n_in,
                              void* d_out, int out_size, void* d_ws, size_t ws_size,
                              hipStream_t stream) {
    (void)n_in; (void)d_ws; (void)ws_size;
    const float* llr  = (const float*)d_in[0];
    const int*   mi   = (const int*)d_in[1];
    float*       out  = (float*)d_out;
    const int B = in_sizes[0] / 7;
    const int block = 256;
    const int grid = (B + block - 1) / block;
    ldpc_bp_kernel<<<grid, block, 0, stream>>>(llr, mi, out, B);
}

// Round 10
// 10.818 us; speedup vs baseline: 1.1402x; 1.0651x over previous
//
#include <hip/hip_runtime.h>
#include <math.h>

// LDPC BP decode, fixed (3x7) H:
//   row A: vars {0,2,4,6}   v0 deg-1
//   row B: vars {1,2,5,6}   v1 deg-1
//   row C: vars {3,4,5,6}   v3 deg-1
// Compute identical (bit-for-bit) to rounds 8/9: p-space Mobius middle
// iterations, log-domain final iteration.
//
// Round-10 changes (I/O + dispatch only):
//   - block = 1024 (16 waves): 256 workgroups = exactly 1 per CU, same
//     4 waves/SIMD occupancy, 1/4 the dispatch events.
//   - vectorized staging: each wave's 448-dword contiguous slice moves
//     global<->LDS as dwordx4 beats (wave base = multiple of 448 dwords
//     -> 16B aligned); 4 VMEM instructions per wave instead of 14.
//     Wave-private LDS slices -> no __syncthreads; per-thread access
//     lane*7+j is stride-7 (coprime to 32) -> bank-conflict-free.

#define LOG2E 1.4426950408889634f
#define LN2   0.6931471805599453f

// p = tanh(m/2) from log2-domain LLR (validated grid path, t<=1 branch)
__device__ __forceinline__ float p_of_llr(float L2) {
    float t  = __builtin_amdgcn_exp2f(-fabsf(L2));
    float u  = __builtin_amdgcn_rcpf(1.0f + t);
    float pm = __builtin_fmaf(-2.0f, t * u, 1.0f);
    return __builtin_copysignf(pm, L2);
}

// tanh addition: comb(a,b) = (a+b)/(1+ab), clamped to [-1,1]
__device__ __forceinline__ float comb(float a, float b) {
    float num = a + b;
    float den = __builtin_fmaf(a, b, 1.0f);
    float r   = num * __builtin_amdgcn_rcpf(den);
    return __builtin_amdgcn_fmed3f(r, -1.0f, 1.0f);
}

// c in log2 units from y = tanh(c/2)
__device__ __forceinline__ float c_of(float y) {
    return __builtin_amdgcn_logf(1.0f + y) - __builtin_amdgcn_logf(1.0f - y);
}

// tot2 pre-filled with L2 (covers iters==0); iters constant-folds at the
// iters==5 call site -> full unroll
__device__ __forceinline__ void decode(int iters, const float L2[7], float tot2[7]) {
    if (iters <= 0) return;

    float pL0  = p_of_llr(L2[0]);
    float pL1  = p_of_llr(L2[1]);
    float pL2v = p_of_llr(L2[2]);
    float pL3  = p_of_llr(L2[3]);
    float pL4v = p_of_llr(L2[4]);
    float pL5v = p_of_llr(L2[5]);
    float pL6v = p_of_llr(L2[6]);

    float pA2 = pL2v, pA4 = pL4v, pA6 = pL6v;
    float pB2 = pL2v, pB5 = pL5v, pB6 = pL6v;
    float pC4 = pL4v, pC5 = pL5v, pC6 = pL6v;

    for (int it = 0; it < iters - 1; ++it) {
        float gA = pL0 * pA2, bA = pA4 * pA6;
        float yA2 = pL0 * bA, yA4 = gA * pA6, yA6 = gA * pA4;
        float gB = pL1 * pB2, bB = pB5 * pB6;
        float yB2 = pL1 * bB, yB5 = gB * pB6, yB6 = gB * pB5;
        float gC = pL3 * pC4, bC = pC5 * pC6;
        float yC4 = pL3 * bC, yC5 = gC * pC6, yC6 = gC * pC5;

        pA2 = comb(pL2v, yB2);
        pB2 = comb(pL2v, yA2);
        pA4 = comb(pL4v, yC4);
        pC4 = comb(pL4v, yA4);
        pB5 = comb(pL5v, yC5);
        pC5 = comb(pL5v, yB5);
        pA6 = comb(comb(pL6v, yB6), yC6);
        pB6 = comb(comb(pL6v, yA6), yC6);
        pC6 = comb(comb(pL6v, yA6), yB6);
    }

    {
        float fA = pL0 * pA2, bA = pA4 * pA6;
        float yA0 = pA2 * bA, yA2 = pL0 * bA, yA4 = fA * pA6, yA6 = fA * pA4;
        float fB = pL1 * pB2, bB = pB5 * pB6;
        float yB1 = pB2 * bB, yB2 = pL1 * bB, yB5 = fB * pB6, yB6 = fB * pB5;
        float fC = pL3 * pC4, bC = pC5 * pC6;
        float yC3 = pC4 * bC, yC4 = pL3 * bC, yC5 = fC * pC6, yC6 = fC * pC5;

        float cA0 = c_of(yA0), cA2 = c_of(yA2), cA4 = c_of(yA4), cA6 = c_of(yA6);
        float cB1 = c_of(yB1), cB2 = c_of(yB2), cB5 = c_of(yB5), cB6 = c_of(yB6);
        float cC3 = c_of(yC3), cC4 = c_of(yC4), cC5 = c_of(yC5), cC6 = c_of(yC6);

        tot2[0] = L2[0] + cA0;
        tot2[1] = L2[1] + cB1;
        tot2[3] = L2[3] + cC3;
        tot2[2] = (L2[2] + cA2) + cB2;
        tot2[4] = (L2[4] + cA4) + cC4;
        tot2[5] = (L2[5] + cB5) + cC5;
        tot2[6] = ((L2[6] + cA6) + cB6) + cC6;
    }
}

__global__ __launch_bounds__(1024) void ldpc_bp_kernel(
        const float* __restrict__ llr,
        const int*   __restrict__ iters_p,
        float*       __restrict__ out,
        int B) {
    __shared__ float lds[16 * 448];          // one 448-dword slice per wave

    const int tid  = threadIdx.x;
    const int wave = tid >> 6;
    const int lane = tid & 63;
    const int waveElemBase = blockIdx.x * 1024 + wave * 64;
    const long dwBase   = (long)waveElemBase * 7;     // multiple of 448
    const long total_dw = (long)B * 7;
    float* wlds = &lds[wave * 448];

    const bool fullWave = (dwBase + 448) <= total_dw;

    // ---- coalesced load ----
    if (fullWave) {
        // 2 dwordx4 beats: beat0 lanes 0..63 -> float4 idx lane,
        // beat1 lanes 0..47 -> float4 idx 64+lane   (448 dwords = 112 x4)
        const float4* g4 = (const float4*)(llr + dwBase);
        float4* l4 = (float4*)wlds;
        l4[lane] = g4[lane];
        if (lane < 48) l4[64 + lane] = g4[64 + lane];
    } else {
#pragma unroll
        for (int j = 0; j < 7; ++j) {
            int  o = j * 64 + lane;
            long g = dwBase + o;
            wlds[o] = (g < total_dw) ? llr[g] : 0.0f;
        }
    }

    const int iters = iters_p[0];

    float L2[7], tot2[7];
#pragma unroll
    for (int j = 0; j < 7; ++j) {
        L2[j]  = wlds[lane * 7 + j] * LOG2E;   // log2-domain LLR
        tot2[j] = L2[j];                       // iters==0 fallback
    }

    if (iters == 5) {
        decode(5, L2, tot2);                   // constant trip -> full unroll
    } else {
        decode(iters, L2, tot2);
    }

    // ---- coalesced store via the same wave-private LDS slice ----
#pragma unroll
    for (int j = 0; j < 7; ++j) {
        wlds[lane * 7 + j] = tot2[j] * LN2;
    }
    if (fullWave) {
        const float4* l4 = (const float4*)wlds;
        float4* g4 = (float4*)(out + dwBase);
        g4[lane] = l4[lane];
        if (lane < 48) g4[64 + lane] = l4[64 + lane];
    } else {
#pragma unroll
        for (int j = 0; j < 7; ++j) {
            int  o = j * 64 + lane;
            long g = dwBase + o;
            if (g < total_dw) out[g] = wlds[o];
        }
    }
}

extern "C" void kernel_launch(void* const* d_in, const int* in_sizes, int n_in,
                              void* d_out, int out_size, void* d_ws, size_t ws_size,
                              hipStream_t stream) {
    (void)n_in; (void)d_ws; (void)ws_size;
    const float* llr  = (const float*)d_in[0];
    const int*   mi   = (const int*)d_in[1];
    float*       out  = (float*)d_out;
    const int B = in_sizes[0] / 7;
    const int block = 1024;
    const int grid = (B + block - 1) / block;
    ldpc_bp_kernel<<<grid, block, 0, stream>>>(llr, mi, out, B);
}

// Round 12
// 10.610 us; speedup vs baseline: 1.1626x; 1.0197x over previous
//
#include <hip/hip_runtime.h>
#include <math.h>

// LDPC BP decode, fixed (3x7) H:
//   row A: vars {0,2,4,6}   v0 deg-1
//   row B: vars {1,2,5,6}   v1 deg-1
//   row C: vars {3,4,5,6}   v3 deg-1
// Compute identical (bit-for-bit) to rounds 8-10: p-space Mobius middle
// iterations, log-domain final iteration.
//
// Round-12 = round-11 with the compile fix: nontemporal stores need a
// native clang vector type (ext_vector_type), not HIP's float4 class.
// Output is written once and never re-read -> NT store skips cache
// write-allocate and shortens the end-of-kernel drain.

#define LOG2E 1.4426950408889634f
#define LN2   0.6931471805599453f

typedef float f32x4 __attribute__((ext_vector_type(4)));

// p = tanh(m/2) from log2-domain LLR (validated grid path, t<=1 branch)
__device__ __forceinline__ float p_of_llr(float L2) {
    float t  = __builtin_amdgcn_exp2f(-fabsf(L2));
    float u  = __builtin_amdgcn_rcpf(1.0f + t);
    float pm = __builtin_fmaf(-2.0f, t * u, 1.0f);
    return __builtin_copysignf(pm, L2);
}

// tanh addition: comb(a,b) = (a+b)/(1+ab), clamped to [-1,1]
__device__ __forceinline__ float comb(float a, float b) {
    float num = a + b;
    float den = __builtin_fmaf(a, b, 1.0f);
    float r   = num * __builtin_amdgcn_rcpf(den);
    return __builtin_amdgcn_fmed3f(r, -1.0f, 1.0f);
}

// c in log2 units from y = tanh(c/2)
__device__ __forceinline__ float c_of(float y) {
    return __builtin_amdgcn_logf(1.0f + y) - __builtin_amdgcn_logf(1.0f - y);
}

// tot2 pre-filled with L2 (covers iters==0); iters constant-folds at the
// iters==5 call site -> full unroll
__device__ __forceinline__ void decode(int iters, const float L2[7], float tot2[7]) {
    if (iters <= 0) return;

    float pL0  = p_of_llr(L2[0]);
    float pL1  = p_of_llr(L2[1]);
    float pL2v = p_of_llr(L2[2]);
    float pL3  = p_of_llr(L2[3]);
    float pL4v = p_of_llr(L2[4]);
    float pL5v = p_of_llr(L2[5]);
    float pL6v = p_of_llr(L2[6]);

    float pA2 = pL2v, pA4 = pL4v, pA6 = pL6v;
    float pB2 = pL2v, pB5 = pL5v, pB6 = pL6v;
    float pC4 = pL4v, pC5 = pL5v, pC6 = pL6v;

    for (int it = 0; it < iters - 1; ++it) {
        float gA = pL0 * pA2, bA = pA4 * pA6;
        float yA2 = pL0 * bA, yA4 = gA * pA6, yA6 = gA * pA4;
        float gB = pL1 * pB2, bB = pB5 * pB6;
        float yB2 = pL1 * bB, yB5 = gB * pB6, yB6 = gB * pB5;
        float gC = pL3 * pC4, bC = pC5 * pC6;
        float yC4 = pL3 * bC, yC5 = gC * pC6, yC6 = gC * pC5;

        pA2 = comb(pL2v, yB2);
        pB2 = comb(pL2v, yA2);
        pA4 = comb(pL4v, yC4);
        pC4 = comb(pL4v, yA4);
        pB5 = comb(pL5v, yC5);
        pC5 = comb(pL5v, yB5);
        pA6 = comb(comb(pL6v, yB6), yC6);
        pB6 = comb(comb(pL6v, yA6), yC6);
        pC6 = comb(comb(pL6v, yA6), yB6);
    }

    {
        float fA = pL0 * pA2, bA = pA4 * pA6;
        float yA0 = pA2 * bA, yA2 = pL0 * bA, yA4 = fA * pA6, yA6 = fA * pA4;
        float fB = pL1 * pB2, bB = pB5 * pB6;
        float yB1 = pB2 * bB, yB2 = pL1 * bB, yB5 = fB * pB6, yB6 = fB * pB5;
        float fC = pL3 * pC4, bC = pC5 * pC6;
        float yC3 = pC4 * bC, yC4 = pL3 * bC, yC5 = fC * pC6, yC6 = fC * pC5;

        float cA0 = c_of(yA0), cA2 = c_of(yA2), cA4 = c_of(yA4), cA6 = c_of(yA6);
        float cB1 = c_of(yB1), cB2 = c_of(yB2), cB5 = c_of(yB5), cB6 = c_of(yB6);
        float cC3 = c_of(yC3), cC4 = c_of(yC4), cC5 = c_of(yC5), cC6 = c_of(yC6);

        tot2[0] = L2[0] + cA0;
        tot2[1] = L2[1] + cB1;
        tot2[3] = L2[3] + cC3;
        tot2[2] = (L2[2] + cA2) + cB2;
        tot2[4] = (L2[4] + cA4) + cC4;
        tot2[5] = (L2[5] + cB5) + cC5;
        tot2[6] = ((L2[6] + cA6) + cB6) + cC6;
    }
}

__global__ __launch_bounds__(1024) void ldpc_bp_kernel(
        const float* __restrict__ llr,
        const int*   __restrict__ iters_p,
        float*       __restrict__ out,
        int B) {
    __shared__ float lds[16 * 448];          // one 448-dword slice per wave

    const int tid  = threadIdx.x;
    const int wave = tid >> 6;
    const int lane = tid & 63;
    const int waveElemBase = blockIdx.x * 1024 + wave * 64;
    const long dwBase   = (long)waveElemBase * 7;     // multiple of 448
    const long total_dw = (long)B * 7;
    float* wlds = &lds[wave * 448];

    const bool fullWave = (dwBase + 448) <= total_dw;

    // ---- coalesced load ----
    if (fullWave) {
        const f32x4* g4 = (const f32x4*)(llr + dwBase);
        f32x4* l4 = (f32x4*)wlds;
        l4[lane] = g4[lane];
        if (lane < 48) l4[64 + lane] = g4[64 + lane];
    } else {
#pragma unroll
        for (int j = 0; j < 7; ++j) {
            int  o = j * 64 + lane;
            long g = dwBase + o;
            wlds[o] = (g < total_dw) ? llr[g] : 0.0f;
        }
    }

    const int iters = iters_p[0];

    float L2[7], tot2[7];
#pragma unroll
    for (int j = 0; j < 7; ++j) {
        L2[j]  = wlds[lane * 7 + j] * LOG2E;   // log2-domain LLR
        tot2[j] = L2[j];                       // iters==0 fallback
    }

    if (iters == 5) {
        decode(5, L2, tot2);                   // constant trip -> full unroll
    } else {
        decode(iters, L2, tot2);
    }

    // ---- coalesced nontemporal store via the wave-private LDS slice ----
#pragma unroll
    for (int j = 0; j < 7; ++j) {
        wlds[lane * 7 + j] = tot2[j] * LN2;
    }
    if (fullWave) {
        const f32x4* l4 = (const f32x4*)wlds;
        f32x4* g4 = (f32x4*)(out + dwBase);
        __builtin_nontemporal_store(l4[lane], &g4[lane]);
        if (lane < 48) __builtin_nontemporal_store(l4[64 + lane], &g4[64 + lane]);
    } else {
#pragma unroll
        for (int j = 0; j < 7; ++j) {
            int  o = j * 64 + lane;
            long g = dwBase + o;
            if (g < total_dw) __builtin_nontemporal_store(wlds[o], &out[g]);
        }
    }
}

extern "C" void kernel_launch(void* const* d_in, const int* in_sizes, int n_in,
                              void* d_out, int out_size, void* d_ws, size_t ws_size,
                              hipStream_t stream) {
    (void)n_in; (void)d_ws; (void)ws_size;
    const float* llr  = (const float*)d_in[0];
    const int*   mi   = (const int*)d_in[1];
    float*       out  = (float*)d_out;
    const int B = in_sizes[0] / 7;
    const int block = 1024;
    const int grid = (B + block - 1) / block;
    ldpc_bp_kernel<<<grid, block, 0, stream>>>(llr, mi, out, B);
}